// Round 1
// baseline (641.220 us; speedup 1.0000x reference)
//
#include <hip/hip_runtime.h>

#define N_NODES 50000
#define NIN 512
#define NH 96
#define NL 32
#define NH2 64

// ws layout in floats:
// [deg N][agg1 N*96][agg2 N*64] <- zeroed every call
// [dis N][h N*96][h23 N*64]
#define OFF_DEG   0
#define OFF_AGG1  (N_NODES)
#define OFF_AGG2  (OFF_AGG1 + N_NODES*NH)
#define OFF_ZEND  (OFF_AGG2 + N_NODES*NH2)      // 8,050,000 floats
#define OFF_DIS   (OFF_ZEND)
#define OFF_H     (OFF_DIS + N_NODES)
#define OFF_H23   (OFF_H + N_NODES*NH)

__global__ void k_zero(float4* __restrict__ p, int n4) {
    int i = blockIdx.x * blockDim.x + threadIdx.x;
    int stride = gridDim.x * blockDim.x;
    for (; i < n4; i += stride) p[i] = make_float4(0.f, 0.f, 0.f, 0.f);
}

__global__ void k_deg(const int* __restrict__ dst, float* __restrict__ deg, int E) {
    int i = blockIdx.x * blockDim.x + threadIdx.x;
    if (i < E) atomicAdd(&deg[dst[i]], 1.0f);
}

__global__ void k_dis(const float* __restrict__ deg, float* __restrict__ dis, int n) {
    int i = blockIdx.x * blockDim.x + threadIdx.x;
    if (i < n) dis[i] = rsqrtf(deg[i] + 1.0f);
}

// h = x @ W1   [N,512] @ [512,96] -> [N,96]
#define BM 64
#define BK 64
__global__ __launch_bounds__(256) void k_gemm1(const float* __restrict__ x,
                                               const float* __restrict__ W,
                                               float* __restrict__ h, int M) {
    __shared__ float xs[BM][BK + 1];   // +1 pad: stride 65 -> conflict-light
    __shared__ float ws[BK][NH];
    int tid = threadIdx.x;
    int m0 = blockIdx.x * BM;
    int tr = tid & 15, tc = tid >> 4;  // 16x16 thread grid: 4 rows x 6 cols each
    float acc[4][6];
#pragma unroll
    for (int i = 0; i < 4; i++)
#pragma unroll
        for (int j = 0; j < 6; j++) acc[i][j] = 0.f;

    for (int k0 = 0; k0 < NIN; k0 += BK) {
        // x tile: 64x64 floats = 1024 float4, 4 per thread
#pragma unroll
        for (int it = 0; it < 4; ++it) {
            int idx = it * 256 + tid;
            int r = idx >> 4;
            int c4 = idx & 15;
            float4 v = make_float4(0.f, 0.f, 0.f, 0.f);
            int gr = m0 + r;
            if (gr < M) v = *reinterpret_cast<const float4*>(&x[gr * NIN + k0 + c4 * 4]);
            xs[r][c4 * 4 + 0] = v.x; xs[r][c4 * 4 + 1] = v.y;
            xs[r][c4 * 4 + 2] = v.z; xs[r][c4 * 4 + 3] = v.w;
        }
        // W tile: 64x96 floats = 1536 float4, 6 per thread
#pragma unroll
        for (int it = 0; it < 6; ++it) {
            int idx = it * 256 + tid;
            int r = idx / 24;
            int c4 = idx % 24;
            float4 v = *reinterpret_cast<const float4*>(&W[(k0 + r) * NH + c4 * 4]);
            *reinterpret_cast<float4*>(&ws[r][c4 * 4]) = v;
        }
        __syncthreads();
#pragma unroll 8
        for (int k = 0; k < BK; k++) {
            float a[4], b[6];
#pragma unroll
            for (int i = 0; i < 4; i++) a[i] = xs[tr * 4 + i][k];
#pragma unroll
            for (int j = 0; j < 6; j++) b[j] = ws[k][tc * 6 + j];
#pragma unroll
            for (int i = 0; i < 4; i++)
#pragma unroll
                for (int j = 0; j < 6; j++) acc[i][j] = fmaf(a[i], b[j], acc[i][j]);
        }
        __syncthreads();
    }
#pragma unroll
    for (int i = 0; i < 4; i++) {
        int gr = m0 + tr * 4 + i;
        if (gr < M) {
#pragma unroll
            for (int j = 0; j < 6; j++) h[gr * NH + tc * 6 + j] = acc[i][j];
        }
    }
}

// per-(edge,feature) scatter: agg1[dst,f] += h[src,f]*dis[src]*dis[dst]
__global__ void k_agg1(const int* __restrict__ src, const int* __restrict__ dst,
                       const float* __restrict__ dis, const float* __restrict__ h,
                       float* __restrict__ agg, int total) {
    int idx = blockIdx.x * blockDim.x + threadIdx.x;
    if (idx >= total) return;
    unsigned e = (unsigned)idx / NH;
    int f = idx - (int)e * NH;
    int s = src[e], d = dst[e];
    float norm = dis[s] * dis[d];
    atomicAdd(&agg[d * NH + f], h[s * NH + f] * norm);
}

// hidden = relu(agg1 + h*dis^2 + b1), written in place over agg1
__global__ void k_selfrelu(float* __restrict__ agg1, const float* __restrict__ h,
                           const float* __restrict__ dis, const float* __restrict__ b1,
                           int total) {
    int idx = blockIdx.x * blockDim.x + threadIdx.x;
    if (idx >= total) return;
    unsigned i = (unsigned)idx / NH;
    int f = idx - (int)i * NH;
    float dv = dis[i];
    float v = agg1[idx] + h[idx] * dv * dv + b1[f];
    agg1[idx] = fmaxf(v, 0.f);
}

// h23 = hidden @ [W_mu | W_logstd]   [N,96] @ [96,64] -> [N,64]
__global__ __launch_bounds__(256) void k_gemm2(const float* __restrict__ hid,
                                               const float* __restrict__ Wmu,
                                               const float* __restrict__ Wls,
                                               float* __restrict__ h23, int M) {
    __shared__ float wl[NH][NH2];   // 24 KB
    int tid = threadIdx.x;
#pragma unroll
    for (int it = 0; it < 6; ++it) {
        int idx = it * 256 + tid;      // 0..1535
        int k = idx >> 4;              // 0..95
        int c4 = idx & 15;             // 16 float4 per 64-wide row
        float4 v;
        if (c4 < 8) v = *reinterpret_cast<const float4*>(&Wmu[k * NL + c4 * 4]);
        else        v = *reinterpret_cast<const float4*>(&Wls[k * NL + (c4 - 8) * 4]);
        *reinterpret_cast<float4*>(&wl[k][c4 * 4]) = v;
    }
    __syncthreads();
    int row = blockIdx.x * 128 + (tid >> 1);
    int half = tid & 1;
    if (row >= M) return;
    float acc[NL];
#pragma unroll
    for (int j = 0; j < NL; j++) acc[j] = 0.f;
    const float* hr = &hid[row * NH];
    for (int k = 0; k < NH; k++) {
        float hv = hr[k];
        const float* w = &wl[k][half * NL];
#pragma unroll
        for (int j = 0; j < NL; j++) acc[j] = fmaf(hv, w[j], acc[j]);
    }
    float4* o4 = reinterpret_cast<float4*>(&h23[row * NH2 + half * NL]);
#pragma unroll
    for (int j4 = 0; j4 < 8; j4++)
        o4[j4] = make_float4(acc[j4 * 4], acc[j4 * 4 + 1], acc[j4 * 4 + 2], acc[j4 * 4 + 3]);
}

// per-(edge,feature) scatter on the 64-wide fused latent
__global__ void k_agg2(const int* __restrict__ src, const int* __restrict__ dst,
                       const float* __restrict__ dis, const float* __restrict__ h23,
                       float* __restrict__ agg, int total) {
    int idx = blockIdx.x * blockDim.x + threadIdx.x;
    if (idx >= total) return;
    int e = idx >> 6;
    int f = idx & 63;
    int s = src[e], d = dst[e];
    float norm = dis[s] * dis[d];
    atomicAdd(&agg[d * NH2 + f], h23[s * NH2 + f] * norm);
}

// out_mu / out_logstd = agg2 + h23*dis^2 + bias
__global__ void k_final(const float* __restrict__ agg2, const float* __restrict__ h23,
                        const float* __restrict__ dis, const float* __restrict__ bmu,
                        const float* __restrict__ bls, float* __restrict__ out, int total) {
    int idx = blockIdx.x * blockDim.x + threadIdx.x;
    if (idx >= total) return;
    int i = idx >> 6;
    int f = idx & 63;
    float dv = dis[i];
    float v = agg2[idx] + h23[idx] * dv * dv + ((f < NL) ? bmu[f] : bls[f - NL]);
    if (f < NL) out[i * NL + f] = v;
    else        out[N_NODES * NL + i * NL + (f - NL)] = v;
}

extern "C" void kernel_launch(void* const* d_in, const int* in_sizes, int n_in,
                              void* d_out, int out_size, void* d_ws, size_t ws_size,
                              hipStream_t stream) {
    const float* x   = (const float*)d_in[0];
    const float* W1  = (const float*)d_in[1];
    const float* b1  = (const float*)d_in[2];
    const float* Wmu = (const float*)d_in[3];
    const float* bmu = (const float*)d_in[4];
    const float* Wls = (const float*)d_in[5];
    const float* bls = (const float*)d_in[6];
    const int*   ei  = (const int*)d_in[7];
    int E = in_sizes[7] / 2;
    const int* src = ei;
    const int* dstp = ei + E;

    float* ws   = (float*)d_ws;
    float* deg  = ws + OFF_DEG;
    float* agg1 = ws + OFF_AGG1;
    float* agg2 = ws + OFF_AGG2;
    float* dis  = ws + OFF_DIS;
    float* h    = ws + OFF_H;
    float* h23  = ws + OFF_H23;
    float* out  = (float*)d_out;

    // zero deg + agg1 + agg2 (contiguous prefix of ws)
    k_zero<<<2048, 256, 0, stream>>>((float4*)ws, OFF_ZEND / 4);

    k_deg<<<(E + 255) / 256, 256, 0, stream>>>(dstp, deg, E);
    k_dis<<<(N_NODES + 255) / 256, 256, 0, stream>>>(deg, dis, N_NODES);

    k_gemm1<<<(N_NODES + BM - 1) / BM, 256, 0, stream>>>(x, W1, h, N_NODES);

    int t1 = E * NH;   // 76.8M
    k_agg1<<<(t1 + 255) / 256, 256, 0, stream>>>(src, dstp, dis, h, agg1, t1);

    int t2 = N_NODES * NH;
    k_selfrelu<<<(t2 + 255) / 256, 256, 0, stream>>>(agg1, h, dis, b1, t2);

    k_gemm2<<<(N_NODES + 127) / 128, 256, 0, stream>>>(agg1, Wmu, Wls, h23, N_NODES);

    int t3 = E * NH2;  // 51.2M
    k_agg2<<<(t3 + 255) / 256, 256, 0, stream>>>(src, dstp, dis, h23, agg2, t3);

    int t4 = N_NODES * NH2;
    k_final<<<(t4 + 255) / 256, 256, 0, stream>>>(agg2, h23, dis, bmu, bls, out, t4);
}

// Round 2
// 459.924 us; speedup vs baseline: 1.3942x; 1.3942x over previous
//
#include <hip/hip_runtime.h>

#define N_NODES 50000
#define NIN 512
#define NH 96
#define NL 32
#define NH2 64
#define NC1 24   // float4 chunks per 96-wide row
#define NC2 16   // float4 chunks per 64-wide row

__global__ void k_zero_int(int* __restrict__ p, int n) {
    int i = blockIdx.x * blockDim.x + threadIdx.x;
    if (i < n) p[i] = 0;
}

__global__ void k_degi(const int* __restrict__ dst, int* __restrict__ degi, int E) {
    int i = blockIdx.x * blockDim.x + threadIdx.x;
    if (i < E) atomicAdd(&degi[dst[i]], 1);
}

// single-block exclusive scan of degi -> rowoff; also dis = rsqrt(deg+1), cur = 0
#define SCAN_T 1024
#define SCAN_C 49   // 49*1024 = 50176 >= 50000
__global__ __launch_bounds__(SCAN_T) void k_scan(const int* __restrict__ degi,
                                                 int* __restrict__ rowoff,
                                                 int* __restrict__ cur,
                                                 float* __restrict__ dis) {
    __shared__ int sums[SCAN_T];
    int t = threadIdx.x;
    int beg = t * SCAN_C, end = min(beg + SCAN_C, N_NODES);
    int s = 0;
    for (int i = beg; i < end; i++) s += degi[i];
    sums[t] = s;
    __syncthreads();
    for (int off = 1; off < SCAN_T; off <<= 1) {
        int v = (t >= off) ? sums[t - off] : 0;
        __syncthreads();
        sums[t] += v;
        __syncthreads();
    }
    int run = sums[t] - s;   // exclusive prefix
    for (int i = beg; i < end; i++) {
        int d = degi[i];
        rowoff[i] = run;
        run += d;
        dis[i] = rsqrtf((float)d + 1.0f);
        cur[i] = 0;
    }
    if (t == SCAN_T - 1) rowoff[N_NODES] = run;
}

// counting-sort bucket pass: esrc/enorm in dst-sorted order
__global__ void k_bucket(const int* __restrict__ src, const int* __restrict__ dst,
                         const int* __restrict__ rowoff, int* __restrict__ cur,
                         const float* __restrict__ dis, int* __restrict__ esrc,
                         float* __restrict__ enorm, int E) {
    int e = blockIdx.x * blockDim.x + threadIdx.x;
    if (e >= E) return;
    int s = src[e], d = dst[e];
    int pos = rowoff[d] + atomicAdd(&cur[d], 1);
    esrc[pos] = s;
    enorm[pos] = dis[s] * dis[d];
}

// h = x @ W1   [N,512] @ [512,96] -> [N,96]
#define BM 64
#define BK 64
__global__ __launch_bounds__(256) void k_gemm1(const float* __restrict__ x,
                                               const float* __restrict__ W,
                                               float* __restrict__ h, int M) {
    __shared__ float xs[BM][BK + 1];
    __shared__ float ws[BK][NH];
    int tid = threadIdx.x;
    int m0 = blockIdx.x * BM;
    int tr = tid & 15, tc = tid >> 4;
    float acc[4][6];
#pragma unroll
    for (int i = 0; i < 4; i++)
#pragma unroll
        for (int j = 0; j < 6; j++) acc[i][j] = 0.f;

    for (int k0 = 0; k0 < NIN; k0 += BK) {
#pragma unroll
        for (int it = 0; it < 4; ++it) {
            int idx = it * 256 + tid;
            int r = idx >> 4;
            int c4 = idx & 15;
            float4 v = make_float4(0.f, 0.f, 0.f, 0.f);
            int gr = m0 + r;
            if (gr < M) v = *reinterpret_cast<const float4*>(&x[gr * NIN + k0 + c4 * 4]);
            xs[r][c4 * 4 + 0] = v.x; xs[r][c4 * 4 + 1] = v.y;
            xs[r][c4 * 4 + 2] = v.z; xs[r][c4 * 4 + 3] = v.w;
        }
#pragma unroll
        for (int it = 0; it < 6; ++it) {
            int idx = it * 256 + tid;
            int r = idx / 24;
            int c4 = idx % 24;
            float4 v = *reinterpret_cast<const float4*>(&W[(k0 + r) * NH + c4 * 4]);
            *reinterpret_cast<float4*>(&ws[r][c4 * 4]) = v;
        }
        __syncthreads();
#pragma unroll 8
        for (int k = 0; k < BK; k++) {
            float a[4], b[6];
#pragma unroll
            for (int i = 0; i < 4; i++) a[i] = xs[tr * 4 + i][k];
#pragma unroll
            for (int j = 0; j < 6; j++) b[j] = ws[k][tc * 6 + j];
#pragma unroll
            for (int i = 0; i < 4; i++)
#pragma unroll
                for (int j = 0; j < 6; j++) acc[i][j] = fmaf(a[i], b[j], acc[i][j]);
        }
        __syncthreads();
    }
#pragma unroll
    for (int i = 0; i < 4; i++) {
        int gr = m0 + tr * 4 + i;
        if (gr < M) {
#pragma unroll
            for (int j = 0; j < 6; j++) h[gr * NH + tc * 6 + j] = acc[i][j];
        }
    }
}

// gather-side aggregation for layer 1, fused self-loop + bias + relu
// 32 lanes per node (24 active), 8 nodes per 256-block
__global__ __launch_bounds__(256) void k_gather1(const float4* __restrict__ h4,
                                                 const int* __restrict__ rowoff,
                                                 const int* __restrict__ esrc,
                                                 const float* __restrict__ enorm,
                                                 const float* __restrict__ dis,
                                                 const float* __restrict__ b1,
                                                 float4* __restrict__ hid4) {
    int tid = threadIdx.x;
    int node = blockIdx.x * 8 + (tid >> 5);
    int c = tid & 31;
    if (node >= N_NODES || c >= NC1) return;
    int p0 = rowoff[node], p1 = rowoff[node + 1];
    float4 acc = make_float4(0.f, 0.f, 0.f, 0.f);
    for (int p = p0; p < p1; p++) {
        int s = esrc[p];
        float w = enorm[p];
        float4 v = h4[s * NC1 + c];
        acc.x = fmaf(v.x, w, acc.x);
        acc.y = fmaf(v.y, w, acc.y);
        acc.z = fmaf(v.z, w, acc.z);
        acc.w = fmaf(v.w, w, acc.w);
    }
    float dv = dis[node];
    float sw = dv * dv;
    float4 hv = h4[node * NC1 + c];
    float4 bv = *reinterpret_cast<const float4*>(&b1[c * 4]);
    acc.x = fmaxf(fmaf(hv.x, sw, acc.x) + bv.x, 0.f);
    acc.y = fmaxf(fmaf(hv.y, sw, acc.y) + bv.y, 0.f);
    acc.z = fmaxf(fmaf(hv.z, sw, acc.z) + bv.z, 0.f);
    acc.w = fmaxf(fmaf(hv.w, sw, acc.w) + bv.w, 0.f);
    hid4[node * NC1 + c] = acc;
}

// h23 = hidden @ [W_mu | W_logstd]   [N,96] @ [96,64] -> [N,64]
__global__ __launch_bounds__(256) void k_gemm2(const float* __restrict__ hid,
                                               const float* __restrict__ Wmu,
                                               const float* __restrict__ Wls,
                                               float* __restrict__ h23, int M) {
    __shared__ float wl[NH][NH2];
    int tid = threadIdx.x;
#pragma unroll
    for (int it = 0; it < 6; ++it) {
        int idx = it * 256 + tid;
        int k = idx >> 4;
        int c4 = idx & 15;
        float4 v;
        if (c4 < 8) v = *reinterpret_cast<const float4*>(&Wmu[k * NL + c4 * 4]);
        else        v = *reinterpret_cast<const float4*>(&Wls[k * NL + (c4 - 8) * 4]);
        *reinterpret_cast<float4*>(&wl[k][c4 * 4]) = v;
    }
    __syncthreads();
    int row = blockIdx.x * 128 + (tid >> 1);
    int half = tid & 1;
    if (row >= M) return;
    float acc[NL];
#pragma unroll
    for (int j = 0; j < NL; j++) acc[j] = 0.f;
    const float* hr = &hid[row * NH];
    for (int k = 0; k < NH; k++) {
        float hv = hr[k];
        const float* w = &wl[k][half * NL];
#pragma unroll
        for (int j = 0; j < NL; j++) acc[j] = fmaf(hv, w[j], acc[j]);
    }
    float4* o4 = reinterpret_cast<float4*>(&h23[row * NH2 + half * NL]);
#pragma unroll
    for (int j4 = 0; j4 < 8; j4++)
        o4[j4] = make_float4(acc[j4 * 4], acc[j4 * 4 + 1], acc[j4 * 4 + 2], acc[j4 * 4 + 3]);
}

// gather-side aggregation for layer 2, fused self-loop + bias + mu/logstd split
// 16 lanes per node, 16 nodes per 256-block
__global__ __launch_bounds__(256) void k_gather2(const float4* __restrict__ h23_4,
                                                 const int* __restrict__ rowoff,
                                                 const int* __restrict__ esrc,
                                                 const float* __restrict__ enorm,
                                                 const float* __restrict__ dis,
                                                 const float* __restrict__ bmu,
                                                 const float* __restrict__ bls,
                                                 float4* __restrict__ out4) {
    int tid = threadIdx.x;
    int node = blockIdx.x * 16 + (tid >> 4);
    int c = tid & 15;
    if (node >= N_NODES) return;
    int p0 = rowoff[node], p1 = rowoff[node + 1];
    float4 acc = make_float4(0.f, 0.f, 0.f, 0.f);
    for (int p = p0; p < p1; p++) {
        int s = esrc[p];
        float w = enorm[p];
        float4 v = h23_4[s * NC2 + c];
        acc.x = fmaf(v.x, w, acc.x);
        acc.y = fmaf(v.y, w, acc.y);
        acc.z = fmaf(v.z, w, acc.z);
        acc.w = fmaf(v.w, w, acc.w);
    }
    float dv = dis[node];
    float sw = dv * dv;
    float4 hv = h23_4[node * NC2 + c];
    float4 bv = (c < 8) ? reinterpret_cast<const float4*>(bmu)[c]
                        : reinterpret_cast<const float4*>(bls)[c - 8];
    acc.x = fmaf(hv.x, sw, acc.x) + bv.x;
    acc.y = fmaf(hv.y, sw, acc.y) + bv.y;
    acc.z = fmaf(hv.z, sw, acc.z) + bv.z;
    acc.w = fmaf(hv.w, sw, acc.w) + bv.w;
    // mu half then logstd half, each [N, 32] floats = 8 float4 per node
    if (c < 8) out4[node * 8 + c] = acc;
    else       out4[N_NODES * 8 + node * 8 + (c - 8)] = acc;
}

extern "C" void kernel_launch(void* const* d_in, const int* in_sizes, int n_in,
                              void* d_out, int out_size, void* d_ws, size_t ws_size,
                              hipStream_t stream) {
    const float* x   = (const float*)d_in[0];
    const float* W1  = (const float*)d_in[1];
    const float* b1  = (const float*)d_in[2];
    const float* Wmu = (const float*)d_in[3];
    const float* bmu = (const float*)d_in[4];
    const float* Wls = (const float*)d_in[5];
    const float* bls = (const float*)d_in[6];
    const int*   ei  = (const int*)d_in[7];
    int E = in_sizes[7] / 2;
    const int* src  = ei;
    const int* dstp = ei + E;

    char* w = (char*)d_ws;
    int* degi   = (int*)w;            w += (size_t)N_NODES * 4;
    int* cur    = (int*)w;            w += (size_t)N_NODES * 4;
    int* rowoff = (int*)w;            w += ((size_t)N_NODES + 4) * 4;  // padded to 16B
    float* dis  = (float*)w;          w += (size_t)N_NODES * 4;
    int* esrc   = (int*)w;            w += (size_t)E * 4;
    float* enorm= (float*)w;          w += (size_t)E * 4;
    float* h    = (float*)w;          w += (size_t)N_NODES * NH * 4;
    float* hid  = (float*)w;          w += (size_t)N_NODES * NH * 4;
    float* h23  = (float*)w;          w += (size_t)N_NODES * NH2 * 4;

    k_zero_int<<<(N_NODES + 255) / 256, 256, 0, stream>>>(degi, N_NODES);
    k_degi<<<(E + 255) / 256, 256, 0, stream>>>(dstp, degi, E);
    k_scan<<<1, SCAN_T, 0, stream>>>(degi, rowoff, cur, dis);
    k_bucket<<<(E + 255) / 256, 256, 0, stream>>>(src, dstp, rowoff, cur, dis, esrc, enorm, E);

    k_gemm1<<<(N_NODES + BM - 1) / BM, 256, 0, stream>>>(x, W1, h, N_NODES);

    k_gather1<<<(N_NODES + 7) / 8, 256, 0, stream>>>(
        (const float4*)h, rowoff, esrc, enorm, dis, b1, (float4*)hid);

    k_gemm2<<<(N_NODES + 127) / 128, 256, 0, stream>>>(hid, Wmu, Wls, h23, N_NODES);

    k_gather2<<<(N_NODES + 15) / 16, 256, 0, stream>>>(
        (const float4*)h23, rowoff, esrc, enorm, dis, bmu, bls, (float4*)d_out);
}

// Round 3
// 426.075 us; speedup vs baseline: 1.5049x; 1.0794x over previous
//
#include <hip/hip_runtime.h>

#define N_NODES 50000
#define NIN 512
#define NH 96
#define NL 32
#define NH2 64
#define NC1 24   // float4 chunks per 96-wide row
#define NC2 16   // float4 chunks per 64-wide row

__global__ void k_zero_int(int* __restrict__ p, int n) {
    int i = blockIdx.x * blockDim.x + threadIdx.x;
    if (i < n) p[i] = 0;
}

__global__ void k_degi(const int* __restrict__ dst, int* __restrict__ degi, int E) {
    int i = blockIdx.x * blockDim.x + threadIdx.x;
    if (i < E) atomicAdd(&degi[dst[i]], 1);
}

// single-block exclusive scan of degi -> rowoff; also dis = rsqrt(deg+1), cur = 0
#define SCAN_T 1024
#define SCAN_C 49   // 49*1024 = 50176 >= 50000
__global__ __launch_bounds__(SCAN_T) void k_scan(const int* __restrict__ degi,
                                                 int* __restrict__ rowoff,
                                                 int* __restrict__ cur,
                                                 float* __restrict__ dis) {
    __shared__ int sums[SCAN_T];
    int t = threadIdx.x;
    int beg = t * SCAN_C, end = min(beg + SCAN_C, N_NODES);
    int s = 0;
    for (int i = beg; i < end; i++) s += degi[i];
    sums[t] = s;
    __syncthreads();
    for (int off = 1; off < SCAN_T; off <<= 1) {
        int v = (t >= off) ? sums[t - off] : 0;
        __syncthreads();
        sums[t] += v;
        __syncthreads();
    }
    int run = sums[t] - s;   // exclusive prefix
    for (int i = beg; i < end; i++) {
        int d = degi[i];
        rowoff[i] = run;
        run += d;
        dis[i] = rsqrtf((float)d + 1.0f);
        cur[i] = 0;
    }
    if (t == SCAN_T - 1) rowoff[N_NODES] = run;
}

// counting-sort bucket pass: esrc/enorm in dst-sorted order
__global__ void k_bucket(const int* __restrict__ src, const int* __restrict__ dst,
                         const int* __restrict__ rowoff, int* __restrict__ cur,
                         const float* __restrict__ dis, int* __restrict__ esrc,
                         float* __restrict__ enorm, int E) {
    int e = blockIdx.x * blockDim.x + threadIdx.x;
    if (e >= E) return;
    int s = src[e], d = dst[e];
    int pos = rowoff[d] + atomicAdd(&cur[d], 1);
    esrc[pos] = s;
    enorm[pos] = dis[s] * dis[d];
}

// h = x @ W1   [N,512] @ [512,96] -> [N,96]
// BM=64 rows/block, BK=32. 256 threads: tr=tid&15 (4 rows), tc=tid>>4 (6 cols).
// x-tile stored TRANSPOSED in LDS (xs[k][row], stride 68) so the a-fragment is
// one ds_read_b128; b-fragment is b128+b64 broadcast. 3 LDS reads : 24 FMA per k.
#define BM1 64
#define BK1 32
__global__ __launch_bounds__(256) void k_gemm1(const float* __restrict__ x,
                                               const float* __restrict__ W,
                                               float* __restrict__ h, int M) {
    __shared__ float xs[BK1][BM1 + 4];   // stride 68 words: 16B-aligned rows
    __shared__ float ws[BK1][NH];
    int tid = threadIdx.x;
    int m0 = blockIdx.x * BM1;
    int tr = tid & 15, tc = tid >> 4;

    float acc[4][6];
#pragma unroll
    for (int i = 0; i < 4; i++)
#pragma unroll
        for (int j = 0; j < 6; j++) acc[i][j] = 0.f;

    float4 gx[2], gw[3];

    // ---- load tile 0 into regs ----
#pragma unroll
    for (int it = 0; it < 2; ++it) {
        int idx = it * 256 + tid;          // 0..511
        int c4 = idx & 7, r = idx >> 3;    // 8 quads per row, 64 rows
        int gr = m0 + r;
        gx[it] = (gr < M) ? *reinterpret_cast<const float4*>(&x[(size_t)gr * NIN + c4 * 4])
                          : make_float4(0.f, 0.f, 0.f, 0.f);
    }
#pragma unroll
    for (int it = 0; it < 3; ++it) {
        int idx = it * 256 + tid;          // 0..767
        int r = idx / 24, c4 = idx % 24;
        gw[it] = *reinterpret_cast<const float4*>(&W[(size_t)r * NH + c4 * 4]);
    }

    for (int t = 0; t < NIN / BK1; ++t) {
        __syncthreads();   // protect previous tile's LDS reads
        // store staged regs
#pragma unroll
        for (int it = 0; it < 2; ++it) {
            int idx = it * 256 + tid;
            int c4 = idx & 7, r = idx >> 3;
            xs[c4 * 4 + 0][r] = gx[it].x;
            xs[c4 * 4 + 1][r] = gx[it].y;
            xs[c4 * 4 + 2][r] = gx[it].z;
            xs[c4 * 4 + 3][r] = gx[it].w;
        }
#pragma unroll
        for (int it = 0; it < 3; ++it) {
            int idx = it * 256 + tid;
            int r = idx / 24, c4 = idx % 24;
            *reinterpret_cast<float4*>(&ws[r][c4 * 4]) = gw[it];
        }
        __syncthreads();

        // issue next tile's global loads (consumed next iteration)
        if (t + 1 < NIN / BK1) {
            int k0 = (t + 1) * BK1;
#pragma unroll
            for (int it = 0; it < 2; ++it) {
                int idx = it * 256 + tid;
                int c4 = idx & 7, r = idx >> 3;
                int gr = m0 + r;
                gx[it] = (gr < M) ? *reinterpret_cast<const float4*>(&x[(size_t)gr * NIN + k0 + c4 * 4])
                                  : make_float4(0.f, 0.f, 0.f, 0.f);
            }
#pragma unroll
            for (int it = 0; it < 3; ++it) {
                int idx = it * 256 + tid;
                int r = idx / 24, c4 = idx % 24;
                gw[it] = *reinterpret_cast<const float4*>(&W[(size_t)(k0 + r) * NH + c4 * 4]);
            }
        }

#pragma unroll 8
        for (int k = 0; k < BK1; k++) {
            float4 a = *reinterpret_cast<const float4*>(&xs[k][tr * 4]);
            float4 b0 = *reinterpret_cast<const float4*>(&ws[k][tc * 6]);
            float2 b1 = *reinterpret_cast<const float2*>(&ws[k][tc * 6 + 4]);
            float av[4] = {a.x, a.y, a.z, a.w};
            float bv[6] = {b0.x, b0.y, b0.z, b0.w, b1.x, b1.y};
#pragma unroll
            for (int i = 0; i < 4; i++)
#pragma unroll
                for (int j = 0; j < 6; j++) acc[i][j] = fmaf(av[i], bv[j], acc[i][j]);
        }
    }

#pragma unroll
    for (int i = 0; i < 4; i++) {
        int gr = m0 + tr * 4 + i;
        if (gr < M) {
            float* hp = &h[(size_t)gr * NH + tc * 6];
            *reinterpret_cast<float2*>(hp + 0) = make_float2(acc[i][0], acc[i][1]);
            *reinterpret_cast<float2*>(hp + 2) = make_float2(acc[i][2], acc[i][3]);
            *reinterpret_cast<float2*>(hp + 4) = make_float2(acc[i][4], acc[i][5]);
        }
    }
}

// gather-side aggregation layer 1, fused self-loop + bias + relu.
// 32 lanes per node (24 active chunks). Edge indices/weights batch-loaded
// coalesced into registers then shfl-broadcast -> row loads pipeline.
__global__ __launch_bounds__(256) void k_gather1(const float4* __restrict__ h4,
                                                 const int* __restrict__ rowoff,
                                                 const int* __restrict__ esrc,
                                                 const float* __restrict__ enorm,
                                                 const float* __restrict__ dis,
                                                 const float* __restrict__ b1,
                                                 float4* __restrict__ hid4) {
    int tid = threadIdx.x;
    int node = blockIdx.x * 8 + (tid >> 5);
    int c = tid & 31;
    if (node >= N_NODES) return;
    int p0 = rowoff[node], p1 = rowoff[node + 1];
    bool act = (c < NC1);
    float4 acc = make_float4(0.f, 0.f, 0.f, 0.f);
    for (int pb = p0; pb < p1; pb += NC1) {
        int nb = min(NC1, p1 - pb);
        int sv = 0; float wv = 0.f;
        if (c < nb) { sv = esrc[pb + c]; wv = enorm[pb + c]; }
#pragma unroll 4
        for (int j = 0; j < nb; j++) {
            int s = __shfl(sv, j, 32);
            float w = __shfl(wv, j, 32);
            if (act) {
                float4 v = h4[(size_t)s * NC1 + c];
                acc.x = fmaf(v.x, w, acc.x);
                acc.y = fmaf(v.y, w, acc.y);
                acc.z = fmaf(v.z, w, acc.z);
                acc.w = fmaf(v.w, w, acc.w);
            }
        }
    }
    if (act) {
        float dv = dis[node];
        float sw = dv * dv;
        float4 hv = h4[(size_t)node * NC1 + c];
        float4 bv = *reinterpret_cast<const float4*>(&b1[c * 4]);
        acc.x = fmaxf(fmaf(hv.x, sw, acc.x) + bv.x, 0.f);
        acc.y = fmaxf(fmaf(hv.y, sw, acc.y) + bv.y, 0.f);
        acc.z = fmaxf(fmaf(hv.z, sw, acc.z) + bv.z, 0.f);
        acc.w = fmaxf(fmaf(hv.w, sw, acc.w) + bv.w, 0.f);
        hid4[(size_t)node * NC1 + c] = acc;
    }
}

// h23 = hidden @ [W_mu | W_logstd]   [N,96] @ [96,64] -> [N,64]
__global__ __launch_bounds__(256) void k_gemm2(const float* __restrict__ hid,
                                               const float* __restrict__ Wmu,
                                               const float* __restrict__ Wls,
                                               float* __restrict__ h23, int M) {
    __shared__ float wl[NH][NH2];
    int tid = threadIdx.x;
#pragma unroll
    for (int it = 0; it < 6; ++it) {
        int idx = it * 256 + tid;
        int k = idx >> 4;
        int c4 = idx & 15;
        float4 v;
        if (c4 < 8) v = *reinterpret_cast<const float4*>(&Wmu[k * NL + c4 * 4]);
        else        v = *reinterpret_cast<const float4*>(&Wls[k * NL + (c4 - 8) * 4]);
        *reinterpret_cast<float4*>(&wl[k][c4 * 4]) = v;
    }
    __syncthreads();
    int row = blockIdx.x * 128 + (tid >> 1);
    int half = tid & 1;
    if (row >= M) return;
    float acc[NL];
#pragma unroll
    for (int j = 0; j < NL; j++) acc[j] = 0.f;
    const float4* hr4 = reinterpret_cast<const float4*>(&hid[(size_t)row * NH]);
#pragma unroll 6
    for (int kq = 0; kq < NH / 4; kq++) {
        float4 hv = hr4[kq];
        float hvv[4] = {hv.x, hv.y, hv.z, hv.w};
#pragma unroll
        for (int kk = 0; kk < 4; kk++) {
            const float* w = &wl[kq * 4 + kk][half * NL];
#pragma unroll
            for (int j = 0; j < NL; j++) acc[j] = fmaf(hvv[kk], w[j], acc[j]);
        }
    }
    float4* o4 = reinterpret_cast<float4*>(&h23[(size_t)row * NH2 + half * NL]);
#pragma unroll
    for (int j4 = 0; j4 < 8; j4++)
        o4[j4] = make_float4(acc[j4 * 4], acc[j4 * 4 + 1], acc[j4 * 4 + 2], acc[j4 * 4 + 3]);
}

// gather-side aggregation layer 2, fused self-loop + bias + mu/logstd split.
// 16 lanes per node; batch-16 edge prefetch + width-16 shfl broadcast.
__global__ __launch_bounds__(256) void k_gather2(const float4* __restrict__ h23_4,
                                                 const int* __restrict__ rowoff,
                                                 const int* __restrict__ esrc,
                                                 const float* __restrict__ enorm,
                                                 const float* __restrict__ dis,
                                                 const float* __restrict__ bmu,
                                                 const float* __restrict__ bls,
                                                 float4* __restrict__ out4) {
    int tid = threadIdx.x;
    int node = blockIdx.x * 16 + (tid >> 4);
    int c = tid & 15;
    if (node >= N_NODES) return;
    int p0 = rowoff[node], p1 = rowoff[node + 1];
    float4 acc = make_float4(0.f, 0.f, 0.f, 0.f);
    for (int pb = p0; pb < p1; pb += NC2) {
        int nb = min(NC2, p1 - pb);
        int sv = 0; float wv = 0.f;
        if (c < nb) { sv = esrc[pb + c]; wv = enorm[pb + c]; }
#pragma unroll 4
        for (int j = 0; j < nb; j++) {
            int s = __shfl(sv, j, 16);
            float w = __shfl(wv, j, 16);
            float4 v = h23_4[(size_t)s * NC2 + c];
            acc.x = fmaf(v.x, w, acc.x);
            acc.y = fmaf(v.y, w, acc.y);
            acc.z = fmaf(v.z, w, acc.z);
            acc.w = fmaf(v.w, w, acc.w);
        }
    }
    float dv = dis[node];
    float sw = dv * dv;
    float4 hv = h23_4[(size_t)node * NC2 + c];
    float4 bv = (c < 8) ? reinterpret_cast<const float4*>(bmu)[c]
                        : reinterpret_cast<const float4*>(bls)[c - 8];
    acc.x = fmaf(hv.x, sw, acc.x) + bv.x;
    acc.y = fmaf(hv.y, sw, acc.y) + bv.y;
    acc.z = fmaf(hv.z, sw, acc.z) + bv.z;
    acc.w = fmaf(hv.w, sw, acc.w) + bv.w;
    if (c < 8) out4[(size_t)node * 8 + c] = acc;
    else       out4[(size_t)N_NODES * 8 + (size_t)node * 8 + (c - 8)] = acc;
}

extern "C" void kernel_launch(void* const* d_in, const int* in_sizes, int n_in,
                              void* d_out, int out_size, void* d_ws, size_t ws_size,
                              hipStream_t stream) {
    const float* x   = (const float*)d_in[0];
    const float* W1  = (const float*)d_in[1];
    const float* b1  = (const float*)d_in[2];
    const float* Wmu = (const float*)d_in[3];
    const float* bmu = (const float*)d_in[4];
    const float* Wls = (const float*)d_in[5];
    const float* bls = (const float*)d_in[6];
    const int*   ei  = (const int*)d_in[7];
    int E = in_sizes[7] / 2;
    const int* src  = ei;
    const int* dstp = ei + E;

    char* w = (char*)d_ws;
    int* degi   = (int*)w;            w += (size_t)N_NODES * 4;
    int* cur    = (int*)w;            w += (size_t)N_NODES * 4;
    int* rowoff = (int*)w;            w += ((size_t)N_NODES + 4) * 4;
    float* dis  = (float*)w;          w += (size_t)N_NODES * 4;
    int* esrc   = (int*)w;            w += (size_t)E * 4;
    float* enorm= (float*)w;          w += (size_t)E * 4;
    float* h    = (float*)w;          w += (size_t)N_NODES * NH * 4;
    float* hid  = (float*)w;          w += (size_t)N_NODES * NH * 4;
    float* h23  = (float*)w;          w += (size_t)N_NODES * NH2 * 4;

    k_zero_int<<<(N_NODES + 255) / 256, 256, 0, stream>>>(degi, N_NODES);
    k_degi<<<(E + 255) / 256, 256, 0, stream>>>(dstp, degi, E);
    k_scan<<<1, SCAN_T, 0, stream>>>(degi, rowoff, cur, dis);
    k_bucket<<<(E + 255) / 256, 256, 0, stream>>>(src, dstp, rowoff, cur, dis, esrc, enorm, E);

    k_gemm1<<<(N_NODES + BM1 - 1) / BM1, 256, 0, stream>>>(x, W1, h, N_NODES);

    k_gather1<<<(N_NODES + 7) / 8, 256, 0, stream>>>(
        (const float4*)h, rowoff, esrc, enorm, dis, b1, (float4*)hid);

    k_gemm2<<<(N_NODES + 127) / 128, 256, 0, stream>>>(hid, Wmu, Wls, h23, N_NODES);

    k_gather2<<<(N_NODES + 15) / 16, 256, 0, stream>>>(
        (const float4*)h23, rowoff, esrc, enorm, dis, bmu, bls, (float4*)d_out);
}

// Round 4
// 304.443 us; speedup vs baseline: 2.1062x; 1.3995x over previous
//
#include <hip/hip_runtime.h>

#define N_NODES 50000
#define NIN 512
#define NH 96
#define NL 32
#define NH2 64
#define NC1 24   // float4 chunks per 96-wide row
#define NC2 16   // float4 chunks per 64-wide row

#define SCAN_BLK 49          // blocks in phase 1/3; each covers 1024 elements
#define SCAN_PER_BLK 1024

__global__ void k_zero_int(int* __restrict__ p, int n) {
    int i = blockIdx.x * blockDim.x + threadIdx.x;
    if (i < n) p[i] = 0;
}

__global__ void k_degi(const int* __restrict__ dst, int* __restrict__ degi, int E) {
    int i = blockIdx.x * blockDim.x + threadIdx.x;
    if (i < E) atomicAdd(&degi[dst[i]], 1);
}

// phase 1: per-block sums of degi (1024 elems/block via int4)
__global__ __launch_bounds__(256) void k_scan1(const int* __restrict__ degi,
                                               int* __restrict__ bsum) {
    __shared__ int red[256];
    int t = threadIdx.x;
    int q = blockIdx.x * 256 + t;          // quad index
    int s = 0;
    if (q * 4 + 3 < N_NODES) {
        int4 v = reinterpret_cast<const int4*>(degi)[q];
        s = v.x + v.y + v.z + v.w;
    } else {
        for (int j = q * 4; j < min(q * 4 + 4, N_NODES); j++) s += degi[j];
    }
    red[t] = s;
    __syncthreads();
    for (int off = 128; off > 0; off >>= 1) {
        if (t < off) red[t] += red[t + off];
        __syncthreads();
    }
    if (t == 0) bsum[blockIdx.x] = red[0];
}

// phase 2: one wave exclusive-scans the 49 block sums
__global__ __launch_bounds__(64) void k_scan2(const int* __restrict__ bsum,
                                              int* __restrict__ boff) {
    int lane = threadIdx.x;
    int v = (lane < SCAN_BLK) ? bsum[lane] : 0;
    int orig = v;
    for (int off = 1; off < 64; off <<= 1) {
        int w = __shfl_up(v, off, 64);
        if (lane >= off) v += w;
    }
    if (lane < SCAN_BLK) boff[lane] = v - orig;   // exclusive
}

// phase 3: block-local exclusive scan + boff, emit rowoff/dis/cur (+ rowoff[N])
__global__ __launch_bounds__(256) void k_scan3(const int* __restrict__ degi,
                                               const int* __restrict__ boff,
                                               int* __restrict__ rowoff,
                                               int* __restrict__ cur,
                                               float* __restrict__ dis) {
    __shared__ int sums[256];
    int t = threadIdx.x;
    int q = blockIdx.x * 256 + t;
    int d[4] = {0, 0, 0, 0};
    if (q * 4 + 3 < N_NODES) {
        int4 v = reinterpret_cast<const int4*>(degi)[q];
        d[0] = v.x; d[1] = v.y; d[2] = v.z; d[3] = v.w;
    } else {
        for (int j = 0; j < 4; j++)
            if (q * 4 + j < N_NODES) d[j] = degi[q * 4 + j];
    }
    int tsum = d[0] + d[1] + d[2] + d[3];
    sums[t] = tsum;
    __syncthreads();
    // Hillis-Steele inclusive scan over thread sums
    for (int off = 1; off < 256; off <<= 1) {
        int v = (t >= off) ? sums[t - off] : 0;
        __syncthreads();
        sums[t] += v;
        __syncthreads();
    }
    int run = boff[blockIdx.x] + sums[t] - tsum;   // exclusive global prefix
#pragma unroll
    for (int j = 0; j < 4; j++) {
        int i = q * 4 + j;
        if (i < N_NODES) {
            rowoff[i] = run;
            dis[i] = rsqrtf((float)d[j] + 1.0f);
            cur[i] = 0;
            run += d[j];
            if (i == N_NODES - 1) rowoff[N_NODES] = run;
        }
    }
}

// counting-sort bucket pass: esrc/enorm in dst-sorted order
__global__ void k_bucket(const int* __restrict__ src, const int* __restrict__ dst,
                         const int* __restrict__ rowoff, int* __restrict__ cur,
                         const float* __restrict__ dis, int* __restrict__ esrc,
                         float* __restrict__ enorm, int E) {
    int e = blockIdx.x * blockDim.x + threadIdx.x;
    if (e >= E) return;
    int s = src[e], d = dst[e];
    int pos = rowoff[d] + atomicAdd(&cur[d], 1);
    esrc[pos] = s;
    enorm[pos] = dis[s] * dis[d];
}

// h = x @ W1   [N,512] @ [512,96] -> [N,96]
#define BM1 64
#define BK1 32
__global__ __launch_bounds__(256) void k_gemm1(const float* __restrict__ x,
                                               const float* __restrict__ W,
                                               float* __restrict__ h, int M) {
    __shared__ float xs[BK1][BM1 + 4];   // stride 68 words: 16B-aligned rows
    __shared__ float ws[BK1][NH];
    int tid = threadIdx.x;
    int m0 = blockIdx.x * BM1;
    int tr = tid & 15, tc = tid >> 4;

    float acc[4][6];
#pragma unroll
    for (int i = 0; i < 4; i++)
#pragma unroll
        for (int j = 0; j < 6; j++) acc[i][j] = 0.f;

    float4 gx[2], gw[3];

#pragma unroll
    for (int it = 0; it < 2; ++it) {
        int idx = it * 256 + tid;
        int c4 = idx & 7, r = idx >> 3;
        int gr = m0 + r;
        gx[it] = (gr < M) ? *reinterpret_cast<const float4*>(&x[(size_t)gr * NIN + c4 * 4])
                          : make_float4(0.f, 0.f, 0.f, 0.f);
    }
#pragma unroll
    for (int it = 0; it < 3; ++it) {
        int idx = it * 256 + tid;
        int r = idx / 24, c4 = idx % 24;
        gw[it] = *reinterpret_cast<const float4*>(&W[(size_t)r * NH + c4 * 4]);
    }

    for (int t = 0; t < NIN / BK1; ++t) {
        __syncthreads();
#pragma unroll
        for (int it = 0; it < 2; ++it) {
            int idx = it * 256 + tid;
            int c4 = idx & 7, r = idx >> 3;
            xs[c4 * 4 + 0][r] = gx[it].x;
            xs[c4 * 4 + 1][r] = gx[it].y;
            xs[c4 * 4 + 2][r] = gx[it].z;
            xs[c4 * 4 + 3][r] = gx[it].w;
        }
#pragma unroll
        for (int it = 0; it < 3; ++it) {
            int idx = it * 256 + tid;
            int r = idx / 24, c4 = idx % 24;
            *reinterpret_cast<float4*>(&ws[r][c4 * 4]) = gw[it];
        }
        __syncthreads();

        if (t + 1 < NIN / BK1) {
            int k0 = (t + 1) * BK1;
#pragma unroll
            for (int it = 0; it < 2; ++it) {
                int idx = it * 256 + tid;
                int c4 = idx & 7, r = idx >> 3;
                int gr = m0 + r;
                gx[it] = (gr < M) ? *reinterpret_cast<const float4*>(&x[(size_t)gr * NIN + k0 + c4 * 4])
                                  : make_float4(0.f, 0.f, 0.f, 0.f);
            }
#pragma unroll
            for (int it = 0; it < 3; ++it) {
                int idx = it * 256 + tid;
                int r = idx / 24, c4 = idx % 24;
                gw[it] = *reinterpret_cast<const float4*>(&W[(size_t)(k0 + r) * NH + c4 * 4]);
            }
        }

#pragma unroll 8
        for (int k = 0; k < BK1; k++) {
            float4 a = *reinterpret_cast<const float4*>(&xs[k][tr * 4]);
            float4 b0 = *reinterpret_cast<const float4*>(&ws[k][tc * 6]);
            float2 b1 = *reinterpret_cast<const float2*>(&ws[k][tc * 6 + 4]);
            float av[4] = {a.x, a.y, a.z, a.w};
            float bv[6] = {b0.x, b0.y, b0.z, b0.w, b1.x, b1.y};
#pragma unroll
            for (int i = 0; i < 4; i++)
#pragma unroll
                for (int j = 0; j < 6; j++) acc[i][j] = fmaf(av[i], bv[j], acc[i][j]);
        }
    }

#pragma unroll
    for (int i = 0; i < 4; i++) {
        int gr = m0 + tr * 4 + i;
        if (gr < M) {
            float* hp = &h[(size_t)gr * NH + tc * 6];
            *reinterpret_cast<float2*>(hp + 0) = make_float2(acc[i][0], acc[i][1]);
            *reinterpret_cast<float2*>(hp + 2) = make_float2(acc[i][2], acc[i][3]);
            *reinterpret_cast<float2*>(hp + 4) = make_float2(acc[i][4], acc[i][5]);
        }
    }
}

// gather-side aggregation layer 1, fused self-loop + bias + relu.
__global__ __launch_bounds__(256) void k_gather1(const float4* __restrict__ h4,
                                                 const int* __restrict__ rowoff,
                                                 const int* __restrict__ esrc,
                                                 const float* __restrict__ enorm,
                                                 const float* __restrict__ dis,
                                                 const float* __restrict__ b1,
                                                 float4* __restrict__ hid4) {
    int tid = threadIdx.x;
    int node = blockIdx.x * 8 + (tid >> 5);
    int c = tid & 31;
    if (node >= N_NODES) return;
    int p0 = rowoff[node], p1 = rowoff[node + 1];
    bool act = (c < NC1);
    float4 acc = make_float4(0.f, 0.f, 0.f, 0.f);
    for (int pb = p0; pb < p1; pb += NC1) {
        int nb = min(NC1, p1 - pb);
        int sv = 0; float wv = 0.f;
        if (c < nb) { sv = esrc[pb + c]; wv = enorm[pb + c]; }
#pragma unroll 4
        for (int j = 0; j < nb; j++) {
            int s = __shfl(sv, j, 32);
            float w = __shfl(wv, j, 32);
            if (act) {
                float4 v = h4[(size_t)s * NC1 + c];
                acc.x = fmaf(v.x, w, acc.x);
                acc.y = fmaf(v.y, w, acc.y);
                acc.z = fmaf(v.z, w, acc.z);
                acc.w = fmaf(v.w, w, acc.w);
            }
        }
    }
    if (act) {
        float dv = dis[node];
        float sw = dv * dv;
        float4 hv = h4[(size_t)node * NC1 + c];
        float4 bv = *reinterpret_cast<const float4*>(&b1[c * 4]);
        acc.x = fmaxf(fmaf(hv.x, sw, acc.x) + bv.x, 0.f);
        acc.y = fmaxf(fmaf(hv.y, sw, acc.y) + bv.y, 0.f);
        acc.z = fmaxf(fmaf(hv.z, sw, acc.z) + bv.z, 0.f);
        acc.w = fmaxf(fmaf(hv.w, sw, acc.w) + bv.w, 0.f);
        hid4[(size_t)node * NC1 + c] = acc;
    }
}

// h23 = hidden @ [W_mu | W_logstd]   [N,96] @ [96,64] -> [N,64]
__global__ __launch_bounds__(256) void k_gemm2(const float* __restrict__ hid,
                                               const float* __restrict__ Wmu,
                                               const float* __restrict__ Wls,
                                               float* __restrict__ h23, int M) {
    __shared__ float wl[NH][NH2];
    int tid = threadIdx.x;
#pragma unroll
    for (int it = 0; it < 6; ++it) {
        int idx = it * 256 + tid;
        int k = idx >> 4;
        int c4 = idx & 15;
        float4 v;
        if (c4 < 8) v = *reinterpret_cast<const float4*>(&Wmu[k * NL + c4 * 4]);
        else        v = *reinterpret_cast<const float4*>(&Wls[k * NL + (c4 - 8) * 4]);
        *reinterpret_cast<float4*>(&wl[k][c4 * 4]) = v;
    }
    __syncthreads();
    int row = blockIdx.x * 128 + (tid >> 1);
    int half = tid & 1;
    if (row >= M) return;
    float acc[NL];
#pragma unroll
    for (int j = 0; j < NL; j++) acc[j] = 0.f;
    const float4* hr4 = reinterpret_cast<const float4*>(&hid[(size_t)row * NH]);
#pragma unroll 6
    for (int kq = 0; kq < NH / 4; kq++) {
        float4 hv = hr4[kq];
        float hvv[4] = {hv.x, hv.y, hv.z, hv.w};
#pragma unroll
        for (int kk = 0; kk < 4; kk++) {
            const float* w = &wl[kq * 4 + kk][half * NL];
#pragma unroll
            for (int j = 0; j < NL; j++) acc[j] = fmaf(hvv[kk], w[j], acc[j]);
        }
    }
    float4* o4 = reinterpret_cast<float4*>(&h23[(size_t)row * NH2 + half * NL]);
#pragma unroll
    for (int j4 = 0; j4 < 8; j4++)
        o4[j4] = make_float4(acc[j4 * 4], acc[j4 * 4 + 1], acc[j4 * 4 + 2], acc[j4 * 4 + 3]);
}

// gather-side aggregation layer 2, fused self-loop + bias + mu/logstd split.
__global__ __launch_bounds__(256) void k_gather2(const float4* __restrict__ h23_4,
                                                 const int* __restrict__ rowoff,
                                                 const int* __restrict__ esrc,
                                                 const float* __restrict__ enorm,
                                                 const float* __restrict__ dis,
                                                 const float* __restrict__ bmu,
                                                 const float* __restrict__ bls,
                                                 float4* __restrict__ out4) {
    int tid = threadIdx.x;
    int node = blockIdx.x * 16 + (tid >> 4);
    int c = tid & 15;
    if (node >= N_NODES) return;
    int p0 = rowoff[node], p1 = rowoff[node + 1];
    float4 acc = make_float4(0.f, 0.f, 0.f, 0.f);
    for (int pb = p0; pb < p1; pb += NC2) {
        int nb = min(NC2, p1 - pb);
        int sv = 0; float wv = 0.f;
        if (c < nb) { sv = esrc[pb + c]; wv = enorm[pb + c]; }
#pragma unroll 4
        for (int j = 0; j < nb; j++) {
            int s = __shfl(sv, j, 16);
            float w = __shfl(wv, j, 16);
            float4 v = h23_4[(size_t)s * NC2 + c];
            acc.x = fmaf(v.x, w, acc.x);
            acc.y = fmaf(v.y, w, acc.y);
            acc.z = fmaf(v.z, w, acc.z);
            acc.w = fmaf(v.w, w, acc.w);
        }
    }
    float dv = dis[node];
    float sw = dv * dv;
    float4 hv = h23_4[(size_t)node * NC2 + c];
    float4 bv = (c < 8) ? reinterpret_cast<const float4*>(bmu)[c]
                        : reinterpret_cast<const float4*>(bls)[c - 8];
    acc.x = fmaf(hv.x, sw, acc.x) + bv.x;
    acc.y = fmaf(hv.y, sw, acc.y) + bv.y;
    acc.z = fmaf(hv.z, sw, acc.z) + bv.z;
    acc.w = fmaf(hv.w, sw, acc.w) + bv.w;
    if (c < 8) out4[(size_t)node * 8 + c] = acc;
    else       out4[(size_t)N_NODES * 8 + (size_t)node * 8 + (c - 8)] = acc;
}

extern "C" void kernel_launch(void* const* d_in, const int* in_sizes, int n_in,
                              void* d_out, int out_size, void* d_ws, size_t ws_size,
                              hipStream_t stream) {
    const float* x   = (const float*)d_in[0];
    const float* W1  = (const float*)d_in[1];
    const float* b1  = (const float*)d_in[2];
    const float* Wmu = (const float*)d_in[3];
    const float* bmu = (const float*)d_in[4];
    const float* Wls = (const float*)d_in[5];
    const float* bls = (const float*)d_in[6];
    const int*   ei  = (const int*)d_in[7];
    int E = in_sizes[7] / 2;
    const int* src  = ei;
    const int* dstp = ei + E;

    char* w = (char*)d_ws;
    int* degi   = (int*)w;            w += (size_t)N_NODES * 4;
    int* cur    = (int*)w;            w += (size_t)N_NODES * 4;
    int* rowoff = (int*)w;            w += ((size_t)N_NODES + 4) * 4;
    float* dis  = (float*)w;          w += (size_t)N_NODES * 4;
    int* bsum   = (int*)w;            w += 64 * 4;
    int* boff   = (int*)w;            w += 64 * 4;
    int* esrc   = (int*)w;            w += (size_t)E * 4;
    float* enorm= (float*)w;          w += (size_t)E * 4;
    float* h    = (float*)w;          w += (size_t)N_NODES * NH * 4;
    float* hid  = (float*)w;          w += (size_t)N_NODES * NH * 4;
    float* h23  = (float*)w;          w += (size_t)N_NODES * NH2 * 4;

    k_zero_int<<<(N_NODES + 255) / 256, 256, 0, stream>>>(degi, N_NODES);
    k_degi<<<(E + 255) / 256, 256, 0, stream>>>(dstp, degi, E);
    k_scan1<<<SCAN_BLK, 256, 0, stream>>>(degi, bsum);
    k_scan2<<<1, 64, 0, stream>>>(bsum, boff);
    k_scan3<<<SCAN_BLK, 256, 0, stream>>>(degi, boff, rowoff, cur, dis);
    k_bucket<<<(E + 255) / 256, 256, 0, stream>>>(src, dstp, rowoff, cur, dis, esrc, enorm, E);

    k_gemm1<<<(N_NODES + BM1 - 1) / BM1, 256, 0, stream>>>(x, W1, h, N_NODES);

    k_gather1<<<(N_NODES + 7) / 8, 256, 0, stream>>>(
        (const float4*)h, rowoff, esrc, enorm, dis, b1, (float4*)hid);

    k_gemm2<<<(N_NODES + 127) / 128, 256, 0, stream>>>(hid, Wmu, Wls, h23, N_NODES);

    k_gather2<<<(N_NODES + 15) / 16, 256, 0, stream>>>(
        (const float4*)h23, rowoff, esrc, enorm, dis, bmu, bls, (float4*)d_out);
}

// Round 5
// 300.222 us; speedup vs baseline: 2.1358x; 1.0141x over previous
//
#include <hip/hip_runtime.h>

#define N_NODES 50000
#define NIN 512
#define NH 96
#define NL 32
#define NH2 64
#define NC1 24   // float4 chunks per 96-wide row
#define NC2 16   // float4 chunks per 64-wide row

#define SCAN_BLK 49          // blocks in phase 1/3; each covers 1024 elements

__global__ void k_zero_int(int* __restrict__ p, int n) {
    int i = blockIdx.x * blockDim.x + threadIdx.x;
    if (i < n) p[i] = 0;
}

__global__ void k_degi(const int* __restrict__ dst, int* __restrict__ degi, int E) {
    int i = blockIdx.x * blockDim.x + threadIdx.x;
    if (i < E) atomicAdd(&degi[dst[i]], 1);
}

// phase 1: per-block sums of degi (1024 elems/block via int4)
__global__ __launch_bounds__(256) void k_scan1(const int* __restrict__ degi,
                                               int* __restrict__ bsum) {
    __shared__ int red[256];
    int t = threadIdx.x;
    int q = blockIdx.x * 256 + t;
    int s = 0;
    if (q * 4 + 3 < N_NODES) {
        int4 v = reinterpret_cast<const int4*>(degi)[q];
        s = v.x + v.y + v.z + v.w;
    } else {
        for (int j = q * 4; j < min(q * 4 + 4, N_NODES); j++) s += degi[j];
    }
    red[t] = s;
    __syncthreads();
    for (int off = 128; off > 0; off >>= 1) {
        if (t < off) red[t] += red[t + off];
        __syncthreads();
    }
    if (t == 0) bsum[blockIdx.x] = red[0];
}

// phase 2: one wave exclusive-scans the 49 block sums
__global__ __launch_bounds__(64) void k_scan2(const int* __restrict__ bsum,
                                              int* __restrict__ boff) {
    int lane = threadIdx.x;
    int v = (lane < SCAN_BLK) ? bsum[lane] : 0;
    int orig = v;
    for (int off = 1; off < 64; off <<= 1) {
        int w = __shfl_up(v, off, 64);
        if (lane >= off) v += w;
    }
    if (lane < SCAN_BLK) boff[lane] = v - orig;
}

// phase 3: block-local exclusive scan + boff, emit rowoff/dis/cur (+ rowoff[N])
__global__ __launch_bounds__(256) void k_scan3(const int* __restrict__ degi,
                                               const int* __restrict__ boff,
                                               int* __restrict__ rowoff,
                                               int* __restrict__ cur,
                                               float* __restrict__ dis) {
    __shared__ int sums[256];
    int t = threadIdx.x;
    int q = blockIdx.x * 256 + t;
    int d[4] = {0, 0, 0, 0};
    if (q * 4 + 3 < N_NODES) {
        int4 v = reinterpret_cast<const int4*>(degi)[q];
        d[0] = v.x; d[1] = v.y; d[2] = v.z; d[3] = v.w;
    } else {
        for (int j = 0; j < 4; j++)
            if (q * 4 + j < N_NODES) d[j] = degi[q * 4 + j];
    }
    int tsum = d[0] + d[1] + d[2] + d[3];
    sums[t] = tsum;
    __syncthreads();
    for (int off = 1; off < 256; off <<= 1) {
        int v = (t >= off) ? sums[t - off] : 0;
        __syncthreads();
        sums[t] += v;
        __syncthreads();
    }
    int run = boff[blockIdx.x] + sums[t] - tsum;
#pragma unroll
    for (int j = 0; j < 4; j++) {
        int i = q * 4 + j;
        if (i < N_NODES) {
            rowoff[i] = run;
            dis[i] = rsqrtf((float)d[j] + 1.0f);
            cur[i] = 0;
            run += d[j];
            if (i == N_NODES - 1) rowoff[N_NODES] = run;
        }
    }
}

// counting-sort bucket pass: epack = {src_bits, norm} in dst-sorted order
__global__ void k_bucket(const int* __restrict__ src, const int* __restrict__ dst,
                         const int* __restrict__ rowoff, int* __restrict__ cur,
                         const float* __restrict__ dis, float2* __restrict__ epack,
                         int E) {
    int e = blockIdx.x * blockDim.x + threadIdx.x;
    if (e >= E) return;
    int s = src[e], d = dst[e];
    int pos = rowoff[d] + atomicAdd(&cur[d], 1);
    epack[pos] = make_float2(__int_as_float(s), dis[s] * dis[d]);
}

// h = x @ W1   [N,512] @ [512,96] -> [N,96]
// LDS-free: lane <-> row (64 rows/block), wave <-> 24-col W slice (uniform -> s_load).
// A streamed from global per-lane (L1-shared across the block's 4 waves).
#define BM1 64
__global__ __launch_bounds__(256) void k_gemm1(const float* __restrict__ x,
                                               const float* __restrict__ W,
                                               float* __restrict__ h, int M) {
    int tid = threadIdx.x;
    int lane = tid & 63;
    int wave = tid >> 6;                              // 0..3
    int c0 = __builtin_amdgcn_readfirstlane(wave * 24);
    int row = blockIdx.x * BM1 + lane;
    int rc = min(row, M - 1);
    const float4* xr = reinterpret_cast<const float4*>(x + (size_t)rc * NIN);

    float acc[24];
#pragma unroll
    for (int j = 0; j < 24; j++) acc[j] = 0.f;

    for (int kc = 0; kc < NIN / 16; ++kc) {           // 32 chunks x 16 k
        float a[16];
#pragma unroll
        for (int q = 0; q < 4; q++) {
            float4 t = xr[kc * 4 + q];
            a[q * 4 + 0] = t.x; a[q * 4 + 1] = t.y;
            a[q * 4 + 2] = t.z; a[q * 4 + 3] = t.w;
        }
#pragma unroll
        for (int kk = 0; kk < 16; ++kk) {
            const float4* bp = reinterpret_cast<const float4*>(
                W + (size_t)(kc * 16 + kk) * NH + c0);
            float4 b0 = bp[0], b1 = bp[1], b2 = bp[2];
            float4 b3 = bp[3], b4 = bp[4], b5 = bp[5];
            float av = a[kk];
            acc[0]  = fmaf(av, b0.x, acc[0]);  acc[1]  = fmaf(av, b0.y, acc[1]);
            acc[2]  = fmaf(av, b0.z, acc[2]);  acc[3]  = fmaf(av, b0.w, acc[3]);
            acc[4]  = fmaf(av, b1.x, acc[4]);  acc[5]  = fmaf(av, b1.y, acc[5]);
            acc[6]  = fmaf(av, b1.z, acc[6]);  acc[7]  = fmaf(av, b1.w, acc[7]);
            acc[8]  = fmaf(av, b2.x, acc[8]);  acc[9]  = fmaf(av, b2.y, acc[9]);
            acc[10] = fmaf(av, b2.z, acc[10]); acc[11] = fmaf(av, b2.w, acc[11]);
            acc[12] = fmaf(av, b3.x, acc[12]); acc[13] = fmaf(av, b3.y, acc[13]);
            acc[14] = fmaf(av, b3.z, acc[14]); acc[15] = fmaf(av, b3.w, acc[15]);
            acc[16] = fmaf(av, b4.x, acc[16]); acc[17] = fmaf(av, b4.y, acc[17]);
            acc[18] = fmaf(av, b4.z, acc[18]); acc[19] = fmaf(av, b4.w, acc[19]);
            acc[20] = fmaf(av, b5.x, acc[20]); acc[21] = fmaf(av, b5.y, acc[21]);
            acc[22] = fmaf(av, b5.z, acc[22]); acc[23] = fmaf(av, b5.w, acc[23]);
        }
    }

    if (row < M) {
        float* hp = h + (size_t)row * NH + c0;
#pragma unroll
        for (int q = 0; q < 6; q++)
            *reinterpret_cast<float4*>(hp + q * 4) =
                make_float4(acc[q * 4], acc[q * 4 + 1], acc[q * 4 + 2], acc[q * 4 + 3]);
    }
}

// gather-side aggregation layer 1, fused self-loop + bias + relu.
__global__ __launch_bounds__(256) void k_gather1(const float4* __restrict__ h4,
                                                 const int* __restrict__ rowoff,
                                                 const float2* __restrict__ epack,
                                                 const float* __restrict__ dis,
                                                 const float* __restrict__ b1,
                                                 float4* __restrict__ hid4) {
    int tid = threadIdx.x;
    int node = blockIdx.x * 8 + (tid >> 5);
    int c = tid & 31;
    if (node >= N_NODES) return;
    int p0 = rowoff[node], p1 = rowoff[node + 1];
    bool act = (c < NC1);
    float4 acc = make_float4(0.f, 0.f, 0.f, 0.f);
    for (int pb = p0; pb < p1; pb += NC1) {
        int nb = min(NC1, p1 - pb);
        float2 ev = make_float2(0.f, 0.f);
        if (c < nb) ev = epack[pb + c];
#pragma unroll 4
        for (int j = 0; j < nb; j++) {
            int s = __float_as_int(__shfl(ev.x, j, 32));
            float w = __shfl(ev.y, j, 32);
            if (act) {
                float4 v = h4[(size_t)s * NC1 + c];
                acc.x = fmaf(v.x, w, acc.x);
                acc.y = fmaf(v.y, w, acc.y);
                acc.z = fmaf(v.z, w, acc.z);
                acc.w = fmaf(v.w, w, acc.w);
            }
        }
    }
    if (act) {
        float dv = dis[node];
        float sw = dv * dv;
        float4 hv = h4[(size_t)node * NC1 + c];
        float4 bv = *reinterpret_cast<const float4*>(&b1[c * 4]);
        acc.x = fmaxf(fmaf(hv.x, sw, acc.x) + bv.x, 0.f);
        acc.y = fmaxf(fmaf(hv.y, sw, acc.y) + bv.y, 0.f);
        acc.z = fmaxf(fmaf(hv.z, sw, acc.z) + bv.z, 0.f);
        acc.w = fmaxf(fmaf(hv.w, sw, acc.w) + bv.w, 0.f);
        hid4[(size_t)node * NC1 + c] = acc;
    }
}

// h23 = hidden @ [W_mu | W_logstd]   [N,96] @ [96,64] -> [N,64]
__global__ __launch_bounds__(256) void k_gemm2(const float* __restrict__ hid,
                                               const float* __restrict__ Wmu,
                                               const float* __restrict__ Wls,
                                               float* __restrict__ h23, int M) {
    __shared__ float wl[NH][NH2];
    int tid = threadIdx.x;
#pragma unroll
    for (int it = 0; it < 6; ++it) {
        int idx = it * 256 + tid;
        int k = idx >> 4;
        int c4 = idx & 15;
        float4 v;
        if (c4 < 8) v = *reinterpret_cast<const float4*>(&Wmu[k * NL + c4 * 4]);
        else        v = *reinterpret_cast<const float4*>(&Wls[k * NL + (c4 - 8) * 4]);
        *reinterpret_cast<float4*>(&wl[k][c4 * 4]) = v;
    }
    __syncthreads();
    int row = blockIdx.x * 128 + (tid >> 1);
    int half = tid & 1;
    if (row >= M) return;
    float acc[NL];
#pragma unroll
    for (int j = 0; j < NL; j++) acc[j] = 0.f;
    const float4* hr4 = reinterpret_cast<const float4*>(&hid[(size_t)row * NH]);
#pragma unroll 6
    for (int kq = 0; kq < NH / 4; kq++) {
        float4 hv = hr4[kq];
        float hvv[4] = {hv.x, hv.y, hv.z, hv.w};
#pragma unroll
        for (int kk = 0; kk < 4; kk++) {
            const float* w = &wl[kq * 4 + kk][half * NL];
#pragma unroll
            for (int j = 0; j < NL; j++) acc[j] = fmaf(hvv[kk], w[j], acc[j]);
        }
    }
    float4* o4 = reinterpret_cast<float4*>(&h23[(size_t)row * NH2 + half * NL]);
#pragma unroll
    for (int j4 = 0; j4 < 8; j4++)
        o4[j4] = make_float4(acc[j4 * 4], acc[j4 * 4 + 1], acc[j4 * 4 + 2], acc[j4 * 4 + 3]);
}

// gather-side aggregation layer 2, fused self-loop + bias + mu/logstd split.
__global__ __launch_bounds__(256) void k_gather2(const float4* __restrict__ h23_4,
                                                 const int* __restrict__ rowoff,
                                                 const float2* __restrict__ epack,
                                                 const float* __restrict__ dis,
                                                 const float* __restrict__ bmu,
                                                 const float* __restrict__ bls,
                                                 float4* __restrict__ out4) {
    int tid = threadIdx.x;
    int node = blockIdx.x * 16 + (tid >> 4);
    int c = tid & 15;
    if (node >= N_NODES) return;
    int p0 = rowoff[node], p1 = rowoff[node + 1];
    float4 acc = make_float4(0.f, 0.f, 0.f, 0.f);
    for (int pb = p0; pb < p1; pb += NC2) {
        int nb = min(NC2, p1 - pb);
        float2 ev = make_float2(0.f, 0.f);
        if (c < nb) ev = epack[pb + c];
#pragma unroll 4
        for (int j = 0; j < nb; j++) {
            int s = __float_as_int(__shfl(ev.x, j, 16));
            float w = __shfl(ev.y, j, 16);
            float4 v = h23_4[(size_t)s * NC2 + c];
            acc.x = fmaf(v.x, w, acc.x);
            acc.y = fmaf(v.y, w, acc.y);
            acc.z = fmaf(v.z, w, acc.z);
            acc.w = fmaf(v.w, w, acc.w);
        }
    }
    float dv = dis[node];
    float sw = dv * dv;
    float4 hv = h23_4[(size_t)node * NC2 + c];
    float4 bv = (c < 8) ? reinterpret_cast<const float4*>(bmu)[c]
                        : reinterpret_cast<const float4*>(bls)[c - 8];
    acc.x = fmaf(hv.x, sw, acc.x) + bv.x;
    acc.y = fmaf(hv.y, sw, acc.y) + bv.y;
    acc.z = fmaf(hv.z, sw, acc.z) + bv.z;
    acc.w = fmaf(hv.w, sw, acc.w) + bv.w;
    if (c < 8) out4[(size_t)node * 8 + c] = acc;
    else       out4[(size_t)N_NODES * 8 + (size_t)node * 8 + (c - 8)] = acc;
}

extern "C" void kernel_launch(void* const* d_in, const int* in_sizes, int n_in,
                              void* d_out, int out_size, void* d_ws, size_t ws_size,
                              hipStream_t stream) {
    const float* x   = (const float*)d_in[0];
    const float* W1  = (const float*)d_in[1];
    const float* b1  = (const float*)d_in[2];
    const float* Wmu = (const float*)d_in[3];
    const float* bmu = (const float*)d_in[4];
    const float* Wls = (const float*)d_in[5];
    const float* bls = (const float*)d_in[6];
    const int*   ei  = (const int*)d_in[7];
    int E = in_sizes[7] / 2;
    const int* src  = ei;
    const int* dstp = ei + E;

    char* w = (char*)d_ws;
    int* degi    = (int*)w;     w += (size_t)N_NODES * 4;
    int* cur     = (int*)w;     w += (size_t)N_NODES * 4;
    int* rowoff  = (int*)w;     w += ((size_t)N_NODES + 4) * 4;
    float* dis   = (float*)w;   w += (size_t)N_NODES * 4;
    int* bsum    = (int*)w;     w += 64 * 4;
    int* boff    = (int*)w;     w += 64 * 4;
    float2* epack= (float2*)w;  w += (size_t)E * 8;
    float* h     = (float*)w;   w += (size_t)N_NODES * NH * 4;
    float* hid   = (float*)w;   w += (size_t)N_NODES * NH * 4;
    float* h23   = (float*)w;   w += (size_t)N_NODES * NH2 * 4;

    k_zero_int<<<(N_NODES + 255) / 256, 256, 0, stream>>>(degi, N_NODES);
    k_degi<<<(E + 255) / 256, 256, 0, stream>>>(dstp, degi, E);
    k_scan1<<<SCAN_BLK, 256, 0, stream>>>(degi, bsum);
    k_scan2<<<1, 64, 0, stream>>>(bsum, boff);
    k_scan3<<<SCAN_BLK, 256, 0, stream>>>(degi, boff, rowoff, cur, dis);
    k_bucket<<<(E + 255) / 256, 256, 0, stream>>>(src, dstp, rowoff, cur, dis, epack, E);

    k_gemm1<<<(N_NODES + BM1 - 1) / BM1, 256, 0, stream>>>(x, W1, h, N_NODES);

    k_gather1<<<(N_NODES + 7) / 8, 256, 0, stream>>>(
        (const float4*)h, rowoff, epack, dis, b1, (float4*)hid);

    k_gemm2<<<(N_NODES + 127) / 128, 256, 0, stream>>>(hid, Wmu, Wls, h23, N_NODES);

    k_gather2<<<(N_NODES + 15) / 16, 256, 0, stream>>>(
        (const float4*)h23, rowoff, epack, dis, bmu, bls, (float4*)d_out);
}